// Round 3
// baseline (5808.253 us; speedup 1.0000x reference)
//
#include <hip/hip_runtime.h>
#include <hip/hip_bf16.h>

#define VOCAB 50257
#define EMBED 256
#define HIDDEN 128
#define G4 512          // 4*HIDDEN, gate order: i | f | g(tanh) | o
#define BATCH 128
#define SEQ 1024
#define UHALF 64        // hidden units per block in the pair-split

typedef float f32x4 __attribute__((ext_vector_type(4)));

// DPP quad-permute cross-lane ops (VALU pipe -- NOT __shfl_xor, which can
// lower to ds_bpermute and compete with the h reads on the LDS pipe).
__device__ __forceinline__ float dpp_xor1(float x) {   // lane ^ 1 within quad
    return __int_as_float(__builtin_amdgcn_update_dpp(
        0, __float_as_int(x), 0xB1 /*quad_perm(1,0,3,2)*/, 0xF, 0xF, true));
}
__device__ __forceinline__ float dpp_xor2(float x) {   // lane ^ 2 within quad
    return __int_as_float(__builtin_amdgcn_update_dpp(
        0, __float_as_int(x), 0x4E /*quad_perm(2,3,0,1)*/, 0xF, 0xF, true));
}

// ---------------------------------------------------------------------------
// Kernel 1: table[m][n] = dot(emb[m,:], W_ih[n,:]) + b_ih[n] + b_hh[n]
// (unchanged: ~190 us, revisit once the recurrence is fixed)
// ---------------------------------------------------------------------------
#define K1_BM 128
#define K1_BN 64
#define K1_BK 32

__global__ __launch_bounds__(256)
void table_gemm(const float* __restrict__ emb, const float* __restrict__ Wih,
                const float* __restrict__ bih, const float* __restrict__ bhh,
                float* __restrict__ table) {
    __shared__ __align__(16) float As[K1_BK][K1_BM + 4];
    __shared__ __align__(16) float Bs[K1_BK][K1_BN + 4];

    const int nTiles = G4 / K1_BN;            // 8
    const int mt = blockIdx.x / nTiles;
    const int nt = blockIdx.x % nTiles;
    const int m0 = mt * K1_BM, n0 = nt * K1_BN;
    const int tid  = threadIdx.x;
    const int tm   = tid & 15;
    const int tn   = tid >> 4;
    const int lrow = tid >> 3;
    const int lk   = (tid & 7) << 2;

    float acc[8][4];
#pragma unroll
    for (int i = 0; i < 8; ++i)
#pragma unroll
        for (int j = 0; j < 4; ++j) acc[i][j] = 0.f;

    for (int k0 = 0; k0 < EMBED; k0 += K1_BK) {
        __syncthreads();
#pragma unroll
        for (int p = 0; p < 4; ++p) {
            int m  = m0 + p * 32 + lrow;
            int ms = m < VOCAB ? m : VOCAB - 1;
            f32x4 a = *(const f32x4*)(emb + (size_t)ms * EMBED + k0 + lk);
            As[lk + 0][p * 32 + lrow] = a[0];
            As[lk + 1][p * 32 + lrow] = a[1];
            As[lk + 2][p * 32 + lrow] = a[2];
            As[lk + 3][p * 32 + lrow] = a[3];
        }
#pragma unroll
        for (int p = 0; p < 2; ++p) {
            int n = n0 + p * 32 + lrow;
            f32x4 b = *(const f32x4*)(Wih + (size_t)n * EMBED + k0 + lk);
            Bs[lk + 0][p * 32 + lrow] = b[0];
            Bs[lk + 1][p * 32 + lrow] = b[1];
            Bs[lk + 2][p * 32 + lrow] = b[2];
            Bs[lk + 3][p * 32 + lrow] = b[3];
        }
        __syncthreads();
#pragma unroll
        for (int k = 0; k < K1_BK; ++k) {
            f32x4 b4   = *(const f32x4*)&Bs[k][tn * 4];
            f32x4 a4lo = *(const f32x4*)&As[k][tm * 8];
            f32x4 a4hi = *(const f32x4*)&As[k][tm * 8 + 4];
#pragma unroll
            for (int i = 0; i < 4; ++i)
#pragma unroll
                for (int j = 0; j < 4; ++j) {
                    acc[i][j]     += a4lo[i] * b4[j];
                    acc[i + 4][j] += a4hi[i] * b4[j];
                }
        }
    }

    const int nbase = n0 + tn * 4;
    float bias0 = bih[nbase + 0] + bhh[nbase + 0];
    float bias1 = bih[nbase + 1] + bhh[nbase + 1];
    float bias2 = bih[nbase + 2] + bhh[nbase + 2];
    float bias3 = bih[nbase + 3] + bhh[nbase + 3];
#pragma unroll
    for (int i = 0; i < 8; ++i) {
        int m = m0 + tm * 8 + i;
        if (m < VOCAB) {
            f32x4 o;
            o[0] = acc[i][0] + bias0;
            o[1] = acc[i][1] + bias1;
            o[2] = acc[i][2] + bias2;
            o[3] = acc[i][3] + bias3;
            *(f32x4*)(table + (size_t)m * G4 + nbase) = o;
        }
    }
}

// ---------------------------------------------------------------------------
// Kernel 2: pair-split LSTM. 256 blocks x 256 threads; blocks b and b^8
// (same XCD under observed round-robin) cooperate on one batch row.
// Block s owns units [64s,64s+64): quad q = unit, lane i4 = k-chunk, the
// proven round-2 quad matvec/reduce. Per-step h-half exchange through
// agent-scope atomics in d_ws; flags are SIGNED ints so 0xAA poison
// (negative) parks the spin, and flag=t+1 is monotonic per launch.
// Co-residency: 256 blocks of 256 thr trivially all fit -> no deadlock.
// ---------------------------------------------------------------------------
__global__ __launch_bounds__(256)
void lstm_pair(const int* __restrict__ x, const float* __restrict__ table,
               const float* __restrict__ Whh,
               const float* __restrict__ Wfc, const float* __restrict__ bfc,
               float* __restrict__ out, float* hbuf, int* flags) {
    __shared__ __align__(16) float h_s[2][HIDDEN];
    __shared__ int toks[SEQ];

    const int blk = blockIdx.x;
    const int s   = (blk >> 3) & 1;                 // half index
    const int row = (blk & 7) | ((blk >> 4) << 3);  // batch row 0..127
    const int tid = threadIdx.x;
    const int i4  = tid & 3;     // k-chunk slot / xg gate index
    const int q   = tid >> 2;    // local unit 0..63
    const int u   = UHALF * s + q;                  // global unit 0..127

    for (int t = tid; t < SEQ; t += 256) toks[t] = x[row * SEQ + t];

    // W_hh rows {g*128+u}, k-chunk [32*i4,+32) in XOR-permuted j order
    // (proven conflict-free in round 2).
    f32x4 wv[4][8];
#pragma unroll
    for (int g = 0; g < 4; ++g)
#pragma unroll
        for (int j = 0; j < 8; ++j)
            wv[g][j] = *(const f32x4*)(Whh + (size_t)(g * HIDDEN + u) * HIDDEN
                                           + 32 * i4 + 4 * (j ^ (2 * i4)));

    if (tid < HIDDEN) h_s[0][tid] = 0.f;
    float c = 0.f;
    const int lane_off = i4 * HIDDEN + u;   // xg of gate i4, unit u
    __syncthreads();

    float xg_cur = table[(size_t)toks[0] * G4 + lane_off];
    float xg_nxt = table[(size_t)toks[1] * G4 + lane_off];

    float* my_h  = hbuf + (row * 2 + s) * UHALF;
    float* pa_h  = hbuf + (row * 2 + (1 ^ s)) * UHALF;
    int*   my_fl = flags + row * 2 + s;
    int*   pa_fl = flags + row * 2 + (1 ^ s);

    for (int t = 0; t < SEQ; ++t) {
        int   tk2   = toks[(t + 2) & (SEQ - 1)];
        float xg_n2 = table[(size_t)tk2 * G4 + lane_off];

        const float* hb = h_s[t & 1];
        f32x4 hc[8];
#pragma unroll
        for (int j = 0; j < 8; ++j)
            hc[j] = *(const f32x4*)(hb + 32 * i4 + 4 * (j ^ (2 * i4)));

        f32x4 a0 = {0.f,0.f,0.f,0.f}, a1 = {0.f,0.f,0.f,0.f};
        f32x4 a2 = {0.f,0.f,0.f,0.f}, a3 = {0.f,0.f,0.f,0.f};
#pragma unroll
        for (int j = 0; j < 8; ++j) {
            a0 += wv[0][j] * hc[j];
            a1 += wv[1][j] * hc[j];
            a2 += wv[2][j] * hc[j];
            a3 += wv[3][j] * hc[j];
        }
        float p0 = (a0[0] + a0[1]) + (a0[2] + a0[3]);
        float p1 = (a1[0] + a1[1]) + (a1[2] + a1[3]);
        float p2 = (a2[0] + a2[1]) + (a2[2] + a2[3]);
        float p3 = (a3[0] + a3[1]) + (a3[2] + a3[3]);
        p0 += (i4 == 0) ? xg_cur : 0.f;
        p1 += (i4 == 1) ? xg_cur : 0.f;
        p2 += (i4 == 2) ? xg_cur : 0.f;
        p3 += (i4 == 3) ? xg_cur : 0.f;

        // quad reduction (round-2 verbatim)
        float u0 = p0 + dpp_xor1(p0);
        float u1 = p1 + dpp_xor1(p1);
        float u2 = p2 + dpp_xor1(p2);
        float u3 = p3 + dpp_xor1(p3);
        float v0 = (i4 & 1) ? u2 : u0;
        float v1 = (i4 & 1) ? u3 : u1;
        float w0 = v0 + dpp_xor2(v0);
        float w1 = v1 + dpp_xor2(v1);
        float o0 = dpp_xor1(w0);
        float o1 = dpp_xor1(w1);
        float gi = (i4 & 1) ? o0 : w0;
        float gf = (i4 & 1) ? o1 : w1;
        float gg = (i4 & 1) ? w0 : o0;
        float go = (i4 & 1) ? w1 : o1;

        float si = __builtin_amdgcn_rcpf(1.f + __expf(-gi));
        float sf = __builtin_amdgcn_rcpf(1.f + __expf(-gf));
        float so = __builtin_amdgcn_rcpf(1.f + __expf(-go));
        float eg = __expf(2.f * gg);
        float tg = 1.f - 2.f * __builtin_amdgcn_rcpf(eg + 1.f);
        c = sf * c + si * tg;
        float ec = __expf(2.f * c);
        float tc = 1.f - 2.f * __builtin_amdgcn_rcpf(ec + 1.f);
        float h  = so * tc;

        const int nxt = (t + 1) & 1;
        if (i4 == 0) {
            h_s[nxt][u] = h;
            __hip_atomic_store(my_h + q, h, __ATOMIC_RELAXED,
                               __HIP_MEMORY_SCOPE_AGENT);
        }
        __syncthreads();   // all leaders' stores vmcnt-drained before flag
        if (tid == 0)
            __hip_atomic_store(my_fl, t + 1, __ATOMIC_RELEASE,
                               __HIP_MEMORY_SCOPE_AGENT);
        if (tid < UHALF) {                 // wave 0 imports partner half
            if (tid == 0) {
                while (__hip_atomic_load(pa_fl, __ATOMIC_ACQUIRE,
                                         __HIP_MEMORY_SCOPE_AGENT) < t + 1) {}
            }
            // whole wave reconverges after lane0's spin; acquire orders these:
            float hv = __hip_atomic_load(pa_h + tid, __ATOMIC_RELAXED,
                                         __HIP_MEMORY_SCOPE_AGENT);
            h_s[nxt][UHALF * (1 ^ s) + tid] = hv;
        }
        __syncthreads();

        xg_cur = xg_nxt;
        xg_nxt = xg_n2;
    }

    // fused head: full h(T) sits in h_s[0] in both blocks; s==0 writes.
    if (s == 0 && tid < 2) {
        const f32x4* wf = (const f32x4*)(Wfc + tid * HIDDEN);
        const f32x4* h4 = (const f32x4*)h_s[0];
        f32x4 sum = {0.f, 0.f, 0.f, 0.f};
#pragma unroll
        for (int k = 0; k < 32; ++k) sum += wf[k] * h4[k];
        out[row * 2 + tid] = bfc[tid] + ((sum[0] + sum[1]) + (sum[2] + sum[3]));
    }
}

extern "C" void kernel_launch(void* const* d_in, const int* in_sizes, int n_in,
                              void* d_out, int out_size, void* d_ws, size_t ws_size,
                              hipStream_t stream) {
    (void)in_sizes; (void)n_in; (void)out_size; (void)ws_size;
    const int*   x   = (const int*)d_in[0];
    const float* emb = (const float*)d_in[1];
    const float* Wih = (const float*)d_in[2];
    const float* Whh = (const float*)d_in[3];
    const float* bih = (const float*)d_in[4];
    const float* bhh = (const float*)d_in[5];
    const float* Wfc = (const float*)d_in[6];
    const float* bfc = (const float*)d_in[7];
    float* out   = (float*)d_out;

    // d_ws layout: [table 98.2 MB][hbuf 64 KB][flags 1 KB]
    float* table = (float*)d_ws;
    size_t table_elems = (size_t)VOCAB * G4;           // 25,731,584 f32
    float* hbuf  = table + table_elems;                // [128][2][64] f32
    int*   flags = (int*)(hbuf + BATCH * 2 * UHALF);   // [128][2] signed int
    // flags are re-poisoned to 0xAAAAAAAA (negative) before every launch,
    // which is < 1 == first awaited value: spin parks correctly, no init pass.

    const int mTiles = (VOCAB + K1_BM - 1) / K1_BM;   // 393
    const int nTiles = G4 / K1_BN;                    // 8
    table_gemm<<<dim3(mTiles * nTiles), 256, 0, stream>>>(emb, Wih, bih, bhh, table);
    lstm_pair<<<dim3(2 * BATCH), 256, 0, stream>>>(x, table, Whh, Wfc, bfc, out,
                                                   hbuf, flags);
}

// Round 5
// 1352.909 us; speedup vs baseline: 4.2932x; 4.2932x over previous
//
#include <hip/hip_runtime.h>
#include <hip/hip_bf16.h>

#define VOCAB 50257
#define EMBED 256
#define HIDDEN 128
#define G4 512          // 4*HIDDEN, gate order: i | f | g(tanh) | o
#define BATCH 128
#define SEQ 1024

typedef float f32x4 __attribute__((ext_vector_type(4)));
typedef float f32x2 __attribute__((ext_vector_type(2)));

// DPP quad-permute cross-lane ops (VALU pipe -- NOT __shfl_xor, which can
// lower to ds_bpermute and compete with the h reads on the LDS pipe).
__device__ __forceinline__ float dpp_xor1(float x) {   // lane ^ 1 within quad
    return __int_as_float(__builtin_amdgcn_update_dpp(
        0, __float_as_int(x), 0xB1 /*quad_perm(1,0,3,2)*/, 0xF, 0xF, true));
}
__device__ __forceinline__ float dpp_xor2(float x) {   // lane ^ 2 within quad
    return __int_as_float(__builtin_amdgcn_update_dpp(
        0, __float_as_int(x), 0x4E /*quad_perm(2,3,0,1)*/, 0xF, 0xF, true));
}

// ---------------------------------------------------------------------------
// Kernel 1: table[m][n] = dot(emb[m,:], W_ih[n,:]) + b_ih[n] + b_hh[n]
// (unchanged: ~190 us; revisit once the recurrence is near its floor)
// ---------------------------------------------------------------------------
#define K1_BM 128
#define K1_BN 64
#define K1_BK 32

__global__ __launch_bounds__(256)
void table_gemm(const float* __restrict__ emb, const float* __restrict__ Wih,
                const float* __restrict__ bih, const float* __restrict__ bhh,
                float* __restrict__ table) {
    __shared__ __align__(16) float As[K1_BK][K1_BM + 4];
    __shared__ __align__(16) float Bs[K1_BK][K1_BN + 4];

    const int nTiles = G4 / K1_BN;            // 8
    const int mt = blockIdx.x / nTiles;
    const int nt = blockIdx.x % nTiles;
    const int m0 = mt * K1_BM, n0 = nt * K1_BN;
    const int tid  = threadIdx.x;
    const int tm   = tid & 15;
    const int tn   = tid >> 4;
    const int lrow = tid >> 3;
    const int lk   = (tid & 7) << 2;

    float acc[8][4];
#pragma unroll
    for (int i = 0; i < 8; ++i)
#pragma unroll
        for (int j = 0; j < 4; ++j) acc[i][j] = 0.f;

    for (int k0 = 0; k0 < EMBED; k0 += K1_BK) {
        __syncthreads();
#pragma unroll
        for (int p = 0; p < 4; ++p) {
            int m  = m0 + p * 32 + lrow;
            int ms = m < VOCAB ? m : VOCAB - 1;
            f32x4 a = *(const f32x4*)(emb + (size_t)ms * EMBED + k0 + lk);
            As[lk + 0][p * 32 + lrow] = a[0];
            As[lk + 1][p * 32 + lrow] = a[1];
            As[lk + 2][p * 32 + lrow] = a[2];
            As[lk + 3][p * 32 + lrow] = a[3];
        }
#pragma unroll
        for (int p = 0; p < 2; ++p) {
            int n = n0 + p * 32 + lrow;
            f32x4 b = *(const f32x4*)(Wih + (size_t)n * EMBED + k0 + lk);
            Bs[lk + 0][p * 32 + lrow] = b[0];
            Bs[lk + 1][p * 32 + lrow] = b[1];
            Bs[lk + 2][p * 32 + lrow] = b[2];
            Bs[lk + 3][p * 32 + lrow] = b[3];
        }
        __syncthreads();
#pragma unroll
        for (int k = 0; k < K1_BK; ++k) {
            f32x4 b4   = *(const f32x4*)&Bs[k][tn * 4];
            f32x4 a4lo = *(const f32x4*)&As[k][tm * 8];
            f32x4 a4hi = *(const f32x4*)&As[k][tm * 8 + 4];
#pragma unroll
            for (int i = 0; i < 4; ++i)
#pragma unroll
                for (int j = 0; j < 4; ++j) {
                    acc[i][j]     += a4lo[i] * b4[j];
                    acc[i + 4][j] += a4hi[i] * b4[j];
                }
        }
    }

    const int nbase = n0 + tn * 4;
    float bias0 = bih[nbase + 0] + bhh[nbase + 0];
    float bias1 = bih[nbase + 1] + bhh[nbase + 1];
    float bias2 = bih[nbase + 2] + bhh[nbase + 2];
    float bias3 = bih[nbase + 3] + bhh[nbase + 3];
#pragma unroll
    for (int i = 0; i < 8; ++i) {
        int m = m0 + tm * 8 + i;
        if (m < VOCAB) {
            f32x4 o;
            o[0] = acc[i][0] + bias0;
            o[1] = acc[i][1] + bias1;
            o[2] = acc[i][2] + bias2;
            o[3] = acc[i][3] + bias3;
            *(f32x4*)(table + (size_t)m * G4 + nbase) = o;
        }
    }
}

// ---------------------------------------------------------------------------
// Kernel 2: sequential LSTM, 256 threads/block, R=8 rows per thread.
//   Quad Q (tid>>2) owns units {2Q, 2Q+1} = 8 gate rows; lane j (tid&3)
//   keeps k-chunk [32j,32j+32) of all 8 rows in 256 VGPRs (64 f32x4).
//   h reads: 8 ds_read_b128/thread, XOR-permuted chunk order (r^2j) --
//   round-2-proven conflict-free (4 distinct bank-quads, 16-way broadcast).
//   Per-step LDS: 32 wave-insts (~384 cyc) streams under ~660 cyc VALU.
//   Quad reduce: xor1 round (8 vals) -> parity fold -> xor2 round.
//   Lane j handles unit 2Q+(j&1) (2-lane redundant). 1 barrier/step.
// ---------------------------------------------------------------------------
__global__ __launch_bounds__(256, 1)
void lstm_seq(const int* __restrict__ x, const float* __restrict__ table,
              const float* __restrict__ Whh,
              const float* __restrict__ Wfc, const float* __restrict__ bfc,
              float* __restrict__ out) {
    __shared__ __align__(16) float h_s[2][HIDDEN];
    __shared__ int toks[SEQ];

    const int b   = blockIdx.x;
    const int tid = threadIdx.x;
    const int j   = tid & 3;     // k-chunk lane within quad
    const int Q   = tid >> 2;    // quad 0..63 -> units 2Q, 2Q+1

    for (int t = tid; t < SEQ; t += 256) toks[t] = x[b * SEQ + t];

    // Weights: row m (m=0..7): gate m&3, unit 2Q+(m>>2).
    // Chunk r stored in the XOR-permuted order (r^2j) matching the h reads.
    f32x4 wv[8][8];
#pragma unroll
    for (int m = 0; m < 8; ++m) {
        const float* wrow = Whh + (size_t)((m & 3) * HIDDEN + 2 * Q + (m >> 2)) * HIDDEN;
#pragma unroll
        for (int r = 0; r < 8; ++r)
            wv[m][r] = *(const f32x4*)(wrow + 32 * j + 4 * (r ^ (2 * j)));
    }

    if (tid < HIDDEN) h_s[0][tid] = 0.f;
    float c = 0.f;
    // lane j folds xg of rows j (unit 2Q) and j+4 (unit 2Q+1): adjacent floats
    const int xgoff = j * HIDDEN + 2 * Q;
    __syncthreads();

    f32x2 xg_cur = *(const f32x2*)(table + (size_t)toks[0] * G4 + xgoff);
    f32x2 xg_nxt = *(const f32x2*)(table + (size_t)toks[1] * G4 + xgoff);

    for (int t = 0; t < SEQ; ++t) {
        int   tk2    = toks[(t + 2) & (SEQ - 1)];
        f32x2 xg_n2  = *(const f32x2*)(table + (size_t)tk2 * G4 + xgoff);

        const float* hb = h_s[t & 1];
        f32x4 hc[8];
#pragma unroll
        for (int r = 0; r < 8; ++r)
            hc[r] = *(const f32x4*)(hb + 32 * j + 4 * (r ^ (2 * j)));

        f32x4 a[8];
#pragma unroll
        for (int m = 0; m < 8; ++m) a[m] = (f32x4){0.f, 0.f, 0.f, 0.f};
#pragma unroll
        for (int r = 0; r < 8; ++r)
#pragma unroll
            for (int m = 0; m < 8; ++m)
                a[m] += wv[m][r] * hc[r];

        float p[8];
#pragma unroll
        for (int m = 0; m < 8; ++m)
            p[m] = (a[m][0] + a[m][1]) + (a[m][2] + a[m][3]);
        // fold xg exactly once per row: lane j carries rows j and j+4
        // (compile-time indices + predicated adds -- no runtime indexing)
#pragma unroll
        for (int m = 0; m < 4; ++m) {
            p[m]     += (j == m) ? xg_cur[0] : 0.f;
            p[m + 4] += (j == m) ? xg_cur[1] : 0.f;
        }

        // reduce across the quad: xor1 on 8 values, fold by parity, xor2
        float u[8];
#pragma unroll
        for (int m = 0; m < 8; ++m) u[m] = p[m] + dpp_xor1(p[m]);
        const bool hi = (j & 1);            // lane's unit = 2Q + (j&1)
        float v0 = hi ? u[4] : u[0];        // gate i
        float v1 = hi ? u[5] : u[1];        // gate f
        float v2 = hi ? u[6] : u[2];        // gate g
        float v3 = hi ? u[7] : u[3];        // gate o
        float gi = v0 + dpp_xor2(v0);
        float gf = v1 + dpp_xor2(v1);
        float gg = v2 + dpp_xor2(v2);
        float go = v3 + dpp_xor2(v3);

        // activations + cell update (2-lane redundant per unit: uniform)
        float si = __builtin_amdgcn_rcpf(1.f + __expf(-gi));
        float sf = __builtin_amdgcn_rcpf(1.f + __expf(-gf));
        float so = __builtin_amdgcn_rcpf(1.f + __expf(-go));
        float eg = __expf(2.f * gg);
        float tg = 1.f - 2.f * __builtin_amdgcn_rcpf(eg + 1.f);   // tanh
        c = sf * c + si * tg;
        float ec = __expf(2.f * c);
        float tc = 1.f - 2.f * __builtin_amdgcn_rcpf(ec + 1.f);   // tanh(c)
        float h  = so * tc;

        const int nxt = (t + 1) & 1;
        if (j < 2) h_s[nxt][2 * Q + j] = h;  // 32 consecutive floats per wave
        __syncthreads();                     // single barrier per step

        xg_cur = xg_nxt;
        xg_nxt = xg_n2;
    }

    // fused head: h_T is in h_s[SEQ & 1] == h_s[0]
    if (tid < 2) {
        const f32x4* wf = (const f32x4*)(Wfc + tid * HIDDEN);
        const f32x4* h4 = (const f32x4*)h_s[0];
        f32x4 s = {0.f, 0.f, 0.f, 0.f};
#pragma unroll
        for (int k = 0; k < 32; ++k) s += wf[k] * h4[k];
        out[b * 2 + tid] = bfc[tid] + ((s[0] + s[1]) + (s[2] + s[3]));
    }
}

extern "C" void kernel_launch(void* const* d_in, const int* in_sizes, int n_in,
                              void* d_out, int out_size, void* d_ws, size_t ws_size,
                              hipStream_t stream) {
    (void)in_sizes; (void)n_in; (void)out_size; (void)ws_size;
    const int*   x   = (const int*)d_in[0];
    const float* emb = (const float*)d_in[1];
    const float* Wih = (const float*)d_in[2];
    const float* Whh = (const float*)d_in[3];
    const float* bih = (const float*)d_in[4];
    const float* bhh = (const float*)d_in[5];
    const float* Wfc = (const float*)d_in[6];
    const float* bfc = (const float*)d_in[7];
    float* out   = (float*)d_out;
    float* table = (float*)d_ws;    // 50257*512*4 B = 98.2 MB scratch

    const int mTiles = (VOCAB + K1_BM - 1) / K1_BM;   // 393
    const int nTiles = G4 / K1_BN;                    // 8
    table_gemm<<<dim3(mTiles * nTiles), 256, 0, stream>>>(emb, Wih, bih, bhh, table);
    lstm_seq<<<dim3(BATCH), 256, 0, stream>>>(x, table, Whh, Wfc, bfc, out);
}

// Round 6
// 978.783 us; speedup vs baseline: 5.9342x; 1.3822x over previous
//
#include <hip/hip_runtime.h>
#include <hip/hip_bf16.h>

#define VOCAB 50257
#define EMBED 256
#define HIDDEN 128
#define G4 512          // 4*HIDDEN, gate order: i | f | g(tanh) | o
#define BATCH 128
#define SEQ 1024

typedef float f32x4 __attribute__((ext_vector_type(4)));
typedef float f32x2 __attribute__((ext_vector_type(2)));

// DPP quad-permute helpers (VALU pipe). Butterfly adds proven in R2 (absmax 3.8e-6).
__device__ __forceinline__ float dpp_xor1(float x) {
    return __int_as_float(__builtin_amdgcn_update_dpp(
        0, __float_as_int(x), 0xB1 /*quad_perm(1,0,3,2)*/, 0xF, 0xF, true));
}
__device__ __forceinline__ float dpp_xor2(float x) {
    return __int_as_float(__builtin_amdgcn_update_dpp(
        0, __float_as_int(x), 0x4E /*quad_perm(2,3,0,1)*/, 0xF, 0xF, true));
}
// quad broadcasts: all 4 lanes of a quad get lane k's value
__device__ __forceinline__ float dpp_bc0(float x) {
    return __int_as_float(__builtin_amdgcn_update_dpp(
        0, __float_as_int(x), 0x00, 0xF, 0xF, true));
}
__device__ __forceinline__ float dpp_bc1(float x) {
    return __int_as_float(__builtin_amdgcn_update_dpp(
        0, __float_as_int(x), 0x55, 0xF, 0xF, true));
}
__device__ __forceinline__ float dpp_bc2(float x) {
    return __int_as_float(__builtin_amdgcn_update_dpp(
        0, __float_as_int(x), 0xAA, 0xF, 0xF, true));
}
__device__ __forceinline__ float dpp_bc3(float x) {
    return __int_as_float(__builtin_amdgcn_update_dpp(
        0, __float_as_int(x), 0xFF, 0xF, 0xF, true));
}
// lane ^ 4 exchange (documented BitMode pattern: xor4 -> 0x101F)
__device__ __forceinline__ float swz_xor4(float x) {
    return __int_as_float(__builtin_amdgcn_ds_swizzle(__float_as_int(x), 0x101F));
}

// ---------------------------------------------------------------------------
// Kernel 1: table[m][n] = dot(emb[m,:], W_ih[n,:]) + b_ih[n] + b_hh[n]
// (unchanged: ~190-210 us)
// ---------------------------------------------------------------------------
#define K1_BM 128
#define K1_BN 64
#define K1_BK 32

__global__ __launch_bounds__(256)
void table_gemm(const float* __restrict__ emb, const float* __restrict__ Wih,
                const float* __restrict__ bih, const float* __restrict__ bhh,
                float* __restrict__ table) {
    __shared__ __align__(16) float As[K1_BK][K1_BM + 4];
    __shared__ __align__(16) float Bs[K1_BK][K1_BN + 4];

    const int nTiles = G4 / K1_BN;            // 8
    const int mt = blockIdx.x / nTiles;
    const int nt = blockIdx.x % nTiles;
    const int m0 = mt * K1_BM, n0 = nt * K1_BN;
    const int tid  = threadIdx.x;
    const int tm   = tid & 15;
    const int tn   = tid >> 4;
    const int lrow = tid >> 3;
    const int lk   = (tid & 7) << 2;

    float acc[8][4];
#pragma unroll
    for (int i = 0; i < 8; ++i)
#pragma unroll
        for (int j = 0; j < 4; ++j) acc[i][j] = 0.f;

    for (int k0 = 0; k0 < EMBED; k0 += K1_BK) {
        __syncthreads();
#pragma unroll
        for (int p = 0; p < 4; ++p) {
            int m  = m0 + p * 32 + lrow;
            int ms = m < VOCAB ? m : VOCAB - 1;
            f32x4 a = *(const f32x4*)(emb + (size_t)ms * EMBED + k0 + lk);
            As[lk + 0][p * 32 + lrow] = a[0];
            As[lk + 1][p * 32 + lrow] = a[1];
            As[lk + 2][p * 32 + lrow] = a[2];
            As[lk + 3][p * 32 + lrow] = a[3];
        }
#pragma unroll
        for (int p = 0; p < 2; ++p) {
            int n = n0 + p * 32 + lrow;
            f32x4 b = *(const f32x4*)(Wih + (size_t)n * EMBED + k0 + lk);
            Bs[lk + 0][p * 32 + lrow] = b[0];
            Bs[lk + 1][p * 32 + lrow] = b[1];
            Bs[lk + 2][p * 32 + lrow] = b[2];
            Bs[lk + 3][p * 32 + lrow] = b[3];
        }
        __syncthreads();
#pragma unroll
        for (int k = 0; k < K1_BK; ++k) {
            f32x4 b4   = *(const f32x4*)&Bs[k][tn * 4];
            f32x4 a4lo = *(const f32x4*)&As[k][tm * 8];
            f32x4 a4hi = *(const f32x4*)&As[k][tm * 8 + 4];
#pragma unroll
            for (int i = 0; i < 4; ++i)
#pragma unroll
                for (int j = 0; j < 4; ++j) {
                    acc[i][j]     += a4lo[i] * b4[j];
                    acc[i + 4][j] += a4hi[i] * b4[j];
                }
        }
    }

    const int nbase = n0 + tn * 4;
    float bias0 = bih[nbase + 0] + bhh[nbase + 0];
    float bias1 = bih[nbase + 1] + bhh[nbase + 1];
    float bias2 = bih[nbase + 2] + bhh[nbase + 2];
    float bias3 = bih[nbase + 3] + bhh[nbase + 3];
#pragma unroll
    for (int i = 0; i < 8; ++i) {
        int m = m0 + tm * 8 + i;
        if (m < VOCAB) {
            f32x4 o;
            o[0] = acc[i][0] + bias0;
            o[1] = acc[i][1] + bias1;
            o[2] = acc[i][2] + bias2;
            o[3] = acc[i][3] + bias3;
            *(f32x4*)(table + (size_t)m * G4 + nbase) = o;
        }
    }
}

// ---------------------------------------------------------------------------
// Kernel 2: sequential LSTM, 512 threads, 8-lane k-split, R=8 rows/thread.
//   Group g8 = tid>>3 owns units {2g8, 2g8+1}; lane j = tid&7 holds k-chunk
//   [16j,16j+16) of all 8 gate rows -> 128 weight VGPRs (fits v0-v255).
//   h reads: 4 ds_read_b128/thread in slot order r = s ^ (j>>1):
//     bank-quad(j,r) = (j&1)*4 + r -> at each slot the 8 j-classes cover
//     all 32 banks; 8-way same-address broadcast within a class is free.
//   Reduce: xor1+xor2 DPP butterfly -> one ds_swizzle(lane^4) exchange
//   (send the opposite-half partial) -> pre = mine + recv + xg (folded once).
//   Gates redistributed by 4 DPP quad-broadcasts; update 4-lane redundant.
//   1 barrier/step (h double-buffer). Serial model: ~475 LDS + ~640 VALU.
// ---------------------------------------------------------------------------
__global__ __launch_bounds__(512, 2)
void lstm_seq(const int* __restrict__ x, const float* __restrict__ table,
              const float* __restrict__ Whh,
              const float* __restrict__ Wfc, const float* __restrict__ bfc,
              float* __restrict__ out) {
    __shared__ __align__(16) float h_s[2][HIDDEN];
    __shared__ int toks[SEQ];

    const int b   = blockIdx.x;
    const int tid = threadIdx.x;
    const int j   = tid & 7;     // k-lane within group
    const int g8  = tid >> 3;    // group 0..63 -> units 2g8, 2g8+1

    for (int t = tid; t < SEQ; t += 512) toks[t] = x[b * SEQ + t];

    // row m (m=0..7): gate (m&3), unit 2g8+(m>>2).
    // chunk slot s holds k-subchunk (s ^ (j>>1)) -- matches the h read order.
    f32x4 wv[8][4];
#pragma unroll
    for (int m = 0; m < 8; ++m) {
        const float* wrow =
            Whh + (size_t)((m & 3) * HIDDEN + 2 * g8 + (m >> 2)) * HIDDEN + 16 * j;
#pragma unroll
        for (int s = 0; s < 4; ++s)
            wv[m][s] = *(const f32x4*)(wrow + 4 * ((s ^ (j >> 1)) & 3));
    }

    if (tid < HIDDEN) h_s[0][tid] = 0.f;
    float c = 0.f;
    // lane j's final row is row j = gate (j&3), unit 2g8+(j>>2):
    const int xgoff = (j & 3) * HIDDEN + 2 * g8 + (j >> 2);
    __syncthreads();

    float xg_cur = table[(size_t)toks[0] * G4 + xgoff];
    float xg_nxt = table[(size_t)toks[1] * G4 + xgoff];

    for (int t = 0; t < SEQ; ++t) {
        int   tk2   = toks[(t + 2) & (SEQ - 1)];
        float xg_n2 = table[(size_t)tk2 * G4 + xgoff];

        // h chunk: 16 floats at [16j,16j+16), slot-permuted for bank spread
        const float* hb = h_s[t & 1] + 16 * j;
        f32x4 hc[4];
#pragma unroll
        for (int s = 0; s < 4; ++s)
            hc[s] = *(const f32x4*)(hb + 4 * ((s ^ (j >> 1)) & 3));

        // 8 row-partials over this lane's 16 h values
        f32x4 acc[8];
#pragma unroll
        for (int m = 0; m < 8; ++m) acc[m] = (f32x4){0.f, 0.f, 0.f, 0.f};
#pragma unroll
        for (int s = 0; s < 4; ++s)
#pragma unroll
            for (int m = 0; m < 8; ++m)
                acc[m] += wv[m][s] * hc[s];

        float p[8];
#pragma unroll
        for (int m = 0; m < 8; ++m)
            p[m] = (acc[m][0] + acc[m][1]) + (acc[m][2] + acc[m][3]);

        // butterfly: xor1 (keep 4 by bit0), xor2 (keep 2 by bit1), xor4 via swizzle
        float u[8];
#pragma unroll
        for (int m = 0; m < 8; ++m) u[m] = p[m] + dpp_xor1(p[m]);
        const bool b0 = (j & 1);
        float q0 = b0 ? u[1] : u[0];     // row 0+b0
        float q1 = b0 ? u[3] : u[2];     // row 2+b0
        float q2 = b0 ? u[5] : u[4];     // row 4+b0
        float q3 = b0 ? u[7] : u[6];     // row 6+b0
        float r0 = q0 + dpp_xor2(q0);
        float r1 = q1 + dpp_xor2(q1);
        float r2 = q2 + dpp_xor2(q2);
        float r3 = q3 + dpp_xor2(q3);
        const bool b1 = (j & 2);
        float lo = b1 ? r1 : r0;         // row (j&3), this quad's half
        float hi = b1 ? r3 : r2;         // row (j&3)+4, this quad's half
        // exchange with lane^4: send the half the PARTNER needs
        const bool up = (j & 4);
        float send = up ? lo : hi;
        float recv = swz_xor4(send);
        float mine = up ? hi : lo;       // row j, this quad's half
        float pre  = mine + recv + xg_cur;   // full row j + xg (folded once)

        // lanes 4b..4b+3 hold gates i,f,g,o of unit 2g8+b: quad-broadcast
        float gi = dpp_bc0(pre);
        float gf = dpp_bc1(pre);
        float gg = dpp_bc2(pre);
        float go = dpp_bc3(pre);

        // activations + cell update (4-lane redundant per unit: uniform)
        float si = __builtin_amdgcn_rcpf(1.f + __expf(-gi));
        float sf = __builtin_amdgcn_rcpf(1.f + __expf(-gf));
        float so = __builtin_amdgcn_rcpf(1.f + __expf(-go));
        float eg = __expf(2.f * gg);
        float tg = 1.f - 2.f * __builtin_amdgcn_rcpf(eg + 1.f);   // tanh
        c = sf * c + si * tg;
        float ec = __expf(2.f * c);
        float tc = 1.f - 2.f * __builtin_amdgcn_rcpf(ec + 1.f);   // tanh(c)
        float h  = so * tc;

        const int nxt = (t + 1) & 1;
        if ((j & 3) == 0)                      // lanes j=0,4: 16 writers/wave,
            h_s[nxt][2 * g8 + (j >> 2)] = h;   // 16 consecutive banks
        __syncthreads();                       // single barrier per step

        xg_cur = xg_nxt;
        xg_nxt = xg_n2;
    }

    // fused head: h_T is in h_s[SEQ & 1] == h_s[0]
    if (tid < 2) {
        const f32x4* wf = (const f32x4*)(Wfc + tid * HIDDEN);
        const f32x4* h4 = (const f32x4*)h_s[0];
        f32x4 s = {0.f, 0.f, 0.f, 0.f};
#pragma unroll
        for (int k = 0; k < 32; ++k) s += wf[k] * h4[k];
        out[b * 2 + tid] = bfc[tid] + ((s[0] + s[1]) + (s[2] + s[3]));
    }
}

extern "C" void kernel_launch(void* const* d_in, const int* in_sizes, int n_in,
                              void* d_out, int out_size, void* d_ws, size_t ws_size,
                              hipStream_t stream) {
    (void)in_sizes; (void)n_in; (void)out_size; (void)ws_size;
    const int*   x   = (const int*)d_in[0];
    const float* emb = (const float*)d_in[1];
    const float* Wih = (const float*)d_in[2];
    const float* Whh = (const float*)d_in[3];
    const float* bih = (const float*)d_in[4];
    const float* bhh = (const float*)d_in[5];
    const float* Wfc = (const float*)d_in[6];
    const float* bfc = (const float*)d_in[7];
    float* out   = (float*)d_out;
    float* table = (float*)d_ws;    // 50257*512*4 B = 98.2 MB scratch

    const int mTiles = (VOCAB + K1_BM - 1) / K1_BM;   // 393
    const int nTiles = G4 / K1_BN;                    // 8
    table_gemm<<<dim3(mTiles * nTiles), 256, 0, stream>>>(emb, Wih, bih, bhh, table);
    lstm_seq<<<dim3(BATCH), 512, 0, stream>>>(x, table, Whh, Wfc, bfc, out);
}

// Round 9
// 860.498 us; speedup vs baseline: 6.7499x; 1.1375x over previous
//
#include <hip/hip_runtime.h>
#include <hip/hip_bf16.h>

#define VOCAB 50257
#define EMBED 256
#define HIDDEN 128
#define G4 512          // 4*HIDDEN, gate order: i | f | g(tanh) | o
#define BATCH 128
#define SEQ 1024

typedef float f32x4 __attribute__((ext_vector_type(4)));
typedef unsigned int u32x4 __attribute__((ext_vector_type(4)));

// DPP quad-permute cross-lane ops (VALU pipe; R2-proven exact, absmax 3.8e-6)
__device__ __forceinline__ float dpp_xor1(float x) {   // lane ^ 1 within quad
    return __int_as_float(__builtin_amdgcn_update_dpp(
        0, __float_as_int(x), 0xB1 /*quad_perm(1,0,3,2)*/, 0xF, 0xF, true));
}
__device__ __forceinline__ float dpp_xor2(float x) {   // lane ^ 2 within quad
    return __int_as_float(__builtin_amdgcn_update_dpp(
        0, __float_as_int(x), 0x4E /*quad_perm(2,3,0,1)*/, 0xF, 0xF, true));
}

__device__ __forceinline__ unsigned int bfbits(float f) {
    __hip_bfloat16 b = __float2bfloat16(f);              // RNE
    return (unsigned int)*reinterpret_cast<unsigned short*>(&b);
}
__device__ __forceinline__ unsigned int pack2(float lo, float hi) {
    return bfbits(lo) | (bfbits(hi) << 16);              // low halfword = even k
}
// D = S0.bf16[0]*S1.bf16[0] + S0.bf16[1]*S1.bf16[1] + S2  (f32 accumulate)
__device__ __forceinline__ float dot2bf(unsigned int a, unsigned int b, float c) {
    float d;
    asm("v_dot2_f32_bf16 %0, %1, %2, %3" : "=v"(d) : "v"(a), "v"(b), "v"(c));
    return d;
}

// ---------------------------------------------------------------------------
// Kernel 1: table[m][n] = dot(emb[m,:], W_ih[n,:]) + b_ih[n] + b_hh[n]
// (unchanged f32 tiled GEMM, ~190 us)
// ---------------------------------------------------------------------------
#define K1_BM 128
#define K1_BN 64
#define K1_BK 32

__global__ __launch_bounds__(256)
void table_gemm(const float* __restrict__ emb, const float* __restrict__ Wih,
                const float* __restrict__ bih, const float* __restrict__ bhh,
                float* __restrict__ table) {
    __shared__ __align__(16) float As[K1_BK][K1_BM + 4];
    __shared__ __align__(16) float Bs[K1_BK][K1_BN + 4];

    const int nTiles = G4 / K1_BN;            // 8
    const int mt = blockIdx.x / nTiles;
    const int nt = blockIdx.x % nTiles;
    const int m0 = mt * K1_BM, n0 = nt * K1_BN;
    const int tid  = threadIdx.x;
    const int tm   = tid & 15;
    const int tn   = tid >> 4;
    const int lrow = tid >> 3;
    const int lk   = (tid & 7) << 2;

    float acc[8][4];
#pragma unroll
    for (int i = 0; i < 8; ++i)
#pragma unroll
        for (int j = 0; j < 4; ++j) acc[i][j] = 0.f;

    for (int k0 = 0; k0 < EMBED; k0 += K1_BK) {
        __syncthreads();
#pragma unroll
        for (int p = 0; p < 4; ++p) {
            int m  = m0 + p * 32 + lrow;
            int ms = m < VOCAB ? m : VOCAB - 1;
            f32x4 a = *(const f32x4*)(emb + (size_t)ms * EMBED + k0 + lk);
            As[lk + 0][p * 32 + lrow] = a[0];
            As[lk + 1][p * 32 + lrow] = a[1];
            As[lk + 2][p * 32 + lrow] = a[2];
            As[lk + 3][p * 32 + lrow] = a[3];
        }
#pragma unroll
        for (int p = 0; p < 2; ++p) {
            int n = n0 + p * 32 + lrow;
            f32x4 b = *(const f32x4*)(Wih + (size_t)n * EMBED + k0 + lk);
            Bs[lk + 0][p * 32 + lrow] = b[0];
            Bs[lk + 1][p * 32 + lrow] = b[1];
            Bs[lk + 2][p * 32 + lrow] = b[2];
            Bs[lk + 3][p * 32 + lrow] = b[3];
        }
        __syncthreads();
#pragma unroll
        for (int k = 0; k < K1_BK; ++k) {
            f32x4 b4   = *(const f32x4*)&Bs[k][tn * 4];
            f32x4 a4lo = *(const f32x4*)&As[k][tm * 8];
            f32x4 a4hi = *(const f32x4*)&As[k][tm * 8 + 4];
#pragma unroll
            for (int i = 0; i < 4; ++i)
#pragma unroll
                for (int j = 0; j < 4; ++j) {
                    acc[i][j]     += a4lo[i] * b4[j];
                    acc[i + 4][j] += a4hi[i] * b4[j];
                }
        }
    }

    const int nbase = n0 + tn * 4;
    float bias0 = bih[nbase + 0] + bhh[nbase + 0];
    float bias1 = bih[nbase + 1] + bhh[nbase + 1];
    float bias2 = bih[nbase + 2] + bhh[nbase + 2];
    float bias3 = bih[nbase + 3] + bhh[nbase + 3];
#pragma unroll
    for (int i = 0; i < 8; ++i) {
        int m = m0 + tm * 8 + i;
        if (m < VOCAB) {
            f32x4 o;
            o[0] = acc[i][0] + bias0;
            o[1] = acc[i][1] + bias1;
            o[2] = acc[i][2] + bias2;
            o[3] = acc[i][3] + bias3;
            *(f32x4*)(table + (size_t)m * G4 + nbase) = o;
        }
    }
}

// ---------------------------------------------------------------------------
// Kernel 2: sequential LSTM, R2 skeleton + bf16 dot2 matvec.
//   Quad Q (tid>>2) = unit; lane j (tid&3) owns k-chunk [32j,32j+32) of the
//   4 gate rows of unit Q, packed bf16x2 -> 64 weight VGPRs (resident).
//   h in LDS as bf16 (256 B/buffer); 4 ds_read_b128/thread in (s^j) chunk
//   order: slot s puts j-classes on 4 disjoint bank-quads -> conflict-free,
//   16-way same-address broadcast. dot2 accumulates scalar f32 (no
//   horizontal adds). Reduce/act: R2 verbatim. 1 barrier/step.
//   FMA issue floor: 64 dot2/thread -> 256 cyc/SIMD (was 512 f32).
// ---------------------------------------------------------------------------
__global__ __launch_bounds__(512, 2)
void lstm_seq(const int* __restrict__ x, const float* __restrict__ table,
              const float* __restrict__ Whh,
              const float* __restrict__ Wfc, const float* __restrict__ bfc,
              float* __restrict__ out) {
    __shared__ __align__(16) unsigned short hbf[2][HIDDEN];  // bf16 h, dbuf
    __shared__ __align__(16) float hf[HIDDEN];               // f32 h_T (head)
    __shared__ int toks[SEQ];

    const int b   = blockIdx.x;
    const int tid = threadIdx.x;
    const int j   = tid & 3;     // k-chunk lane within quad
    const int Q   = tid >> 2;    // unit 0..127

    for (int t = tid; t < SEQ; t += 512) toks[t] = x[b * SEQ + t];

    // Weights: gate m of unit Q, k-chunk [32j,32j+32), packed bf16 pairs.
    // 16B slot s holds 8-value subchunk (s^j)&3 -- matches h read order.
    unsigned int wv[4][4][4];    // [gate][slot][dword] = 64 VGPRs
#pragma unroll
    for (int m = 0; m < 4; ++m) {
        const float* wrow = Whh + (size_t)(m * HIDDEN + Q) * HIDDEN + 32 * j;
#pragma unroll
        for (int s = 0; s < 4; ++s) {
            const int cc = (s ^ j) & 3;
#pragma unroll
            for (int d = 0; d < 4; ++d)
                wv[m][s][d] = pack2(wrow[8 * cc + 2 * d], wrow[8 * cc + 2 * d + 1]);
        }
    }

    if (tid < HIDDEN) hbf[0][tid] = 0;     // bf16 zero
    float c = 0.f;
    const int lane_off = j * HIDDEN + Q;   // xg of gate j, unit Q
    __syncthreads();

    float xg_cur = table[(size_t)toks[0] * G4 + lane_off];
    float xg_nxt = table[(size_t)toks[1] * G4 + lane_off];

    float h = 0.f;
    for (int t = 0; t < SEQ; ++t) {
        int   tk2   = toks[(t + 2) & (SEQ - 1)];
        float xg_n2 = table[(size_t)tk2 * G4 + lane_off];

        // h chunk: 32 bf16 at bytes [64j, 64j+64), slot-permuted order
        const char* hb = (const char*)hbf[t & 1] + 64 * j;
        u32x4 hc[4];
#pragma unroll
        for (int s = 0; s < 4; ++s)
            hc[s] = *(const u32x4*)(hb + 16 * ((s ^ j) & 3));

        // 4 gate-row partials over this lane's 32 h values (scalar f32 acc)
        float a0 = 0.f, a1 = 0.f, a2 = 0.f, a3 = 0.f;
#pragma unroll
        for (int s = 0; s < 4; ++s)
#pragma unroll
            for (int d = 0; d < 4; ++d) {
                a0 = dot2bf(wv[0][s][d], hc[s][d], a0);
                a1 = dot2bf(wv[1][s][d], hc[s][d], a1);
                a2 = dot2bf(wv[2][s][d], hc[s][d], a2);
                a3 = dot2bf(wv[3][s][d], hc[s][d], a3);
            }
        // fold xg exactly once: lane j carries gate row j
        float p0 = a0 + ((j == 0) ? xg_cur : 0.f);
        float p1 = a1 + ((j == 1) ? xg_cur : 0.f);
        float p2 = a2 + ((j == 2) ? xg_cur : 0.f);
        float p3 = a3 + ((j == 3) ? xg_cur : 0.f);

        // quad reduction (R2 verbatim, empirically exact)
        float u0 = p0 + dpp_xor1(p0);
        float u1 = p1 + dpp_xor1(p1);
        float u2 = p2 + dpp_xor1(p2);
        float u3 = p3 + dpp_xor1(p3);
        float v0 = (j & 1) ? u2 : u0;
        float v1 = (j & 1) ? u3 : u1;
        float w0 = v0 + dpp_xor2(v0);
        float w1 = v1 + dpp_xor2(v1);
        float o0 = dpp_xor1(w0);
        float o1 = dpp_xor1(w1);
        float gi = (j & 1) ? o0 : w0;
        float gf = (j & 1) ? o1 : w1;
        float gg = (j & 1) ? w0 : o0;
        float go = (j & 1) ? w1 : o1;

        // activations + cell update (4-lane redundant per unit: uniform)
        float si = __builtin_amdgcn_rcpf(1.f + __expf(-gi));
        float sf = __builtin_amdgcn_rcpf(1.f + __expf(-gf));
        float so = __builtin_amdgcn_rcpf(1.f + __expf(-go));
        float eg = __expf(2.f * gg);
        float tg = 1.f - 2.f * __builtin_amdgcn_rcpf(eg + 1.f);   // tanh
        c = sf * c + si * tg;
        float ec = __expf(2.f * c);
        float tc = 1.f - 2.f * __builtin_amdgcn_rcpf(ec + 1.f);   // tanh(c)
        h = so * tc;

        const int nxt = (t + 1) & 1;
        if (j == 0)
            hbf[nxt][Q] = (unsigned short)bfbits(h);   // 16 writers/wave
        __syncthreads();                               // single barrier/step

        xg_cur = xg_nxt;
        xg_nxt = xg_n2;
    }

    // head needs f32 h_T: park it, then 2-thread dot
    if (j == 0) hf[Q] = h;
    __syncthreads();
    if (tid < 2) {
        const f32x4* wf = (const f32x4*)(Wfc + tid * HIDDEN);
        const f32x4* h4 = (const f32x4*)hf;
        f32x4 s = {0.f, 0.f, 0.f, 0.f};
#pragma unroll
        for (int k = 0; k < 32; ++k) s += wf[k] * h4[k];
        out[b * 2 + tid] = bfc[tid] + ((s[0] + s[1]) + (s[2] + s[3]));
    }
}

extern "C" void kernel_launch(void* const* d_in, const int* in_sizes, int n_in,
                              void* d_out, int out_size, void* d_ws, size_t ws_size,
                              hipStream_t stream) {
    (void)in_sizes; (void)n_in; (void)out_size; (void)ws_size;
    const int*   x   = (const int*)d_in[0];
    const float* emb = (const float*)d_in[1];
    const float* Wih = (const float*)d_in[2];
    const float* Whh = (const float*)d_in[3];
    const float* bih = (const float*)d_in[4];
    const float* bhh = (const float*)d_in[5];
    const float* Wfc = (const float*)d_in[6];
    const float* bfc = (const float*)d_in[7];
    float* out   = (float*)d_out;
    float* table = (float*)d_ws;    // 50257*512*4 B = 98.2 MB scratch

    const int mTiles = (VOCAB + K1_BM - 1) / K1_BM;   // 393
    const int nTiles = G4 / K1_BN;                    // 8
    table_gemm<<<dim3(mTiles * nTiles), 256, 0, stream>>>(emb, Wih, bih, bhh, table);
    lstm_seq<<<dim3(BATCH), 512, 0, stream>>>(x, table, Whh, Wfc, bfc, out);
}

// Round 10
// 859.781 us; speedup vs baseline: 6.7555x; 1.0008x over previous
//
#include <hip/hip_runtime.h>
#include <hip/hip_bf16.h>

#define VOCAB 50257
#define EMBED 256
#define HIDDEN 128
#define G4 512          // 4*HIDDEN, gate order: i | f | g(tanh) | o
#define BATCH 128
#define SEQ 1024

typedef float f32x4 __attribute__((ext_vector_type(4)));
typedef float f32x2 __attribute__((ext_vector_type(2)));
typedef unsigned int u32x4 __attribute__((ext_vector_type(4)));

// DPP quad-permute cross-lane ops (VALU pipe; R2-proven exact)
__device__ __forceinline__ float dpp_xor1(float x) {   // lane ^ 1 within quad
    return __int_as_float(__builtin_amdgcn_update_dpp(
        0, __float_as_int(x), 0xB1 /*quad_perm(1,0,3,2)*/, 0xF, 0xF, true));
}
__device__ __forceinline__ float dpp_xor2(float x) {   // lane ^ 2 within quad
    return __int_as_float(__builtin_amdgcn_update_dpp(
        0, __float_as_int(x), 0x4E /*quad_perm(2,3,0,1)*/, 0xF, 0xF, true));
}
// quad broadcasts (R6-proven)
__device__ __forceinline__ float dpp_bc0(float x) {
    return __int_as_float(__builtin_amdgcn_update_dpp(
        0, __float_as_int(x), 0x00, 0xF, 0xF, true));
}
__device__ __forceinline__ float dpp_bc1(float x) {
    return __int_as_float(__builtin_amdgcn_update_dpp(
        0, __float_as_int(x), 0x55, 0xF, 0xF, true));
}
__device__ __forceinline__ float dpp_bc2(float x) {
    return __int_as_float(__builtin_amdgcn_update_dpp(
        0, __float_as_int(x), 0xAA, 0xF, 0xF, true));
}
__device__ __forceinline__ float dpp_bc3(float x) {
    return __int_as_float(__builtin_amdgcn_update_dpp(
        0, __float_as_int(x), 0xFF, 0xF, 0xF, true));
}

__device__ __forceinline__ unsigned int bfbits(float f) {
    __hip_bfloat16 b = __float2bfloat16(f);              // RNE
    return (unsigned int)*reinterpret_cast<unsigned short*>(&b);
}
__device__ __forceinline__ unsigned int pack2(float lo, float hi) {
    return bfbits(lo) | (bfbits(hi) << 16);              // low halfword = even k
}
// hardware pack: two f32 -> one dword of 2 bf16 (RNE), single VALU inst
__device__ __forceinline__ unsigned int cvt_pk_bf16(float lo, float hi) {
    unsigned int r;
    asm("v_cvt_pk_bf16_f32 %0, %1, %2" : "=v"(r) : "v"(lo), "v"(hi));
    return r;
}
// D = S0.bf16[0]*S1.bf16[0] + S0.bf16[1]*S1.bf16[1] + S2  (f32 accumulate)
__device__ __forceinline__ float dot2bf(unsigned int a, unsigned int b, float c) {
    float d;
    asm("v_dot2_f32_bf16 %0, %1, %2, %3" : "=v"(d) : "v"(a), "v"(b), "v"(c));
    return d;
}

// ---------------------------------------------------------------------------
// Kernel 1: table[m][n] = dot(emb[m,:], W_ih[n,:]) + b_ih[n] + b_hh[n]
// (unchanged f32 tiled GEMM, ~190 us; next target after the recurrence)
// ---------------------------------------------------------------------------
#define K1_BM 128
#define K1_BN 64
#define K1_BK 32

__global__ __launch_bounds__(256)
void table_gemm(const float* __restrict__ emb, const float* __restrict__ Wih,
                const float* __restrict__ bih, const float* __restrict__ bhh,
                float* __restrict__ table) {
    __shared__ __align__(16) float As[K1_BK][K1_BM + 4];
    __shared__ __align__(16) float Bs[K1_BK][K1_BN + 4];

    const int nTiles = G4 / K1_BN;            // 8
    const int mt = blockIdx.x / nTiles;
    const int nt = blockIdx.x % nTiles;
    const int m0 = mt * K1_BM, n0 = nt * K1_BN;
    const int tid  = threadIdx.x;
    const int tm   = tid & 15;
    const int tn   = tid >> 4;
    const int lrow = tid >> 3;
    const int lk   = (tid & 7) << 2;

    float acc[8][4];
#pragma unroll
    for (int i = 0; i < 8; ++i)
#pragma unroll
        for (int j = 0; j < 4; ++j) acc[i][j] = 0.f;

    for (int k0 = 0; k0 < EMBED; k0 += K1_BK) {
        __syncthreads();
#pragma unroll
        for (int p = 0; p < 4; ++p) {
            int m  = m0 + p * 32 + lrow;
            int ms = m < VOCAB ? m : VOCAB - 1;
            f32x4 a = *(const f32x4*)(emb + (size_t)ms * EMBED + k0 + lk);
            As[lk + 0][p * 32 + lrow] = a[0];
            As[lk + 1][p * 32 + lrow] = a[1];
            As[lk + 2][p * 32 + lrow] = a[2];
            As[lk + 3][p * 32 + lrow] = a[3];
        }
#pragma unroll
        for (int p = 0; p < 2; ++p) {
            int n = n0 + p * 32 + lrow;
            f32x4 b = *(const f32x4*)(Wih + (size_t)n * EMBED + k0 + lk);
            Bs[lk + 0][p * 32 + lrow] = b[0];
            Bs[lk + 1][p * 32 + lrow] = b[1];
            Bs[lk + 2][p * 32 + lrow] = b[2];
            Bs[lk + 3][p * 32 + lrow] = b[3];
        }
        __syncthreads();
#pragma unroll
        for (int k = 0; k < K1_BK; ++k) {
            f32x4 b4   = *(const f32x4*)&Bs[k][tn * 4];
            f32x4 a4lo = *(const f32x4*)&As[k][tm * 8];
            f32x4 a4hi = *(const f32x4*)&As[k][tm * 8 + 4];
#pragma unroll
            for (int i = 0; i < 4; ++i)
#pragma unroll
                for (int j = 0; j < 4; ++j) {
                    acc[i][j]     += a4lo[i] * b4[j];
                    acc[i + 4][j] += a4hi[i] * b4[j];
                }
        }
    }

    const int nbase = n0 + tn * 4;
    float bias0 = bih[nbase + 0] + bhh[nbase + 0];
    float bias1 = bih[nbase + 1] + bhh[nbase + 1];
    float bias2 = bih[nbase + 2] + bhh[nbase + 2];
    float bias3 = bih[nbase + 3] + bhh[nbase + 3];
#pragma unroll
    for (int i = 0; i < 8; ++i) {
        int m = m0 + tm * 8 + i;
        if (m < VOCAB) {
            f32x4 o;
            o[0] = acc[i][0] + bias0;
            o[1] = acc[i][1] + bias1;
            o[2] = acc[i][2] + bias2;
            o[3] = acc[i][3] + bias3;
            *(f32x4*)(table + (size_t)m * G4 + nbase) = o;
        }
    }
}

// ---------------------------------------------------------------------------
// Kernel 2: sequential LSTM, 256 threads (1 wave/SIMD), s=4 k-split, R=8.
//   Quad Q (tid>>2) owns units {2Q, 2Q+1}; lane j (tid&3) holds k-chunk
//   [32j,32j+32) of all 8 gate rows, packed bf16 -> 128 weight VGPRs.
//   h in LDS as bf16; 4 ds_read_b128/thread in (s^j) slot order
//   (disjoint bank-quads, 16-way broadcast, conflict-free) -> only
//   16 LDS read insts/step/CU. dot2 f32-accum; quad-only butterfly
//   reduce (no ds_swizzle): lane j ends with full rows {j, j+4};
//   4+4 quad-broadcast DPPs redistribute gates; cvt_pk_bf16 packs both
//   units' h into one predicated ds_write_b32. 1 barrier/step.
// ---------------------------------------------------------------------------
__global__ __launch_bounds__(256, 1)
void lstm_seq(const int* __restrict__ x, const float* __restrict__ table,
              const float* __restrict__ Whh,
              const float* __restrict__ Wfc, const float* __restrict__ bfc,
              float* __restrict__ out) {
    __shared__ __align__(16) unsigned short hbf[2][HIDDEN];  // bf16 h, dbuf
    __shared__ __align__(16) float hf[HIDDEN];               // f32 h_T (head)
    __shared__ int toks[SEQ];

    const int b   = blockIdx.x;
    const int tid = threadIdx.x;
    const int j   = tid & 3;     // k-chunk lane within quad
    const int Q   = tid >> 2;    // quad 0..63 -> units 2Q, 2Q+1

    for (int t = tid; t < SEQ; t += 256) toks[t] = x[b * SEQ + t];

    // Weights: row m (gate m&3, unit 2Q+(m>>2)), k-chunk [32j,+32) packed
    // bf16 pairs; 16B slot s holds 8-value subchunk (s^j) -- matches h reads.
    unsigned int wv[8][4][4];    // [row][slot][dword] = 128 VGPRs
#pragma unroll
    for (int m = 0; m < 8; ++m) {
        const float* wrow =
            Whh + (size_t)((m & 3) * HIDDEN + 2 * Q + (m >> 2)) * HIDDEN + 32 * j;
#pragma unroll
        for (int s = 0; s < 4; ++s) {
            const int cc = (s ^ j) & 3;
#pragma unroll
            for (int d = 0; d < 4; ++d)
                wv[m][s][d] = pack2(wrow[8 * cc + 2 * d], wrow[8 * cc + 2 * d + 1]);
        }
    }

    if (tid < HIDDEN) hbf[0][tid] = 0;     // bf16 zero
    float cA = 0.f, cB = 0.f;              // cell state, units 2Q and 2Q+1
    // lane j folds xg of rows j (unit 2Q) and j+4 (unit 2Q+1): adjacent floats
    const int xgoff = j * HIDDEN + 2 * Q;
    __syncthreads();

    f32x2 xg_cur = *(const f32x2*)(table + (size_t)toks[0] * G4 + xgoff);
    f32x2 xg_nxt = *(const f32x2*)(table + (size_t)toks[1] * G4 + xgoff);

    float hA = 0.f, hB = 0.f;
    for (int t = 0; t < SEQ; ++t) {
        int   tk2   = toks[(t + 2) & (SEQ - 1)];
        f32x2 xg_n2 = *(const f32x2*)(table + (size_t)tk2 * G4 + xgoff);

        // h chunk: 32 bf16 at bytes [64j, 64j+64), slot-permuted order
        const char* hb = (const char*)hbf[t & 1] + 64 * j;
        u32x4 hc[4];
#pragma unroll
        for (int s = 0; s < 4; ++s)
            hc[s] = *(const u32x4*)(hb + 16 * ((s ^ j) & 3));

        // 8 row-partials over this lane's 32 h values (scalar f32 accums)
        float p[8];
#pragma unroll
        for (int m = 0; m < 8; ++m) p[m] = 0.f;
#pragma unroll
        for (int s = 0; s < 4; ++s)
#pragma unroll
            for (int d = 0; d < 4; ++d)
#pragma unroll
                for (int m = 0; m < 8; ++m)
                    p[m] = dot2bf(wv[m][s][d], hc[s][d], p[m]);

        // fold xg exactly once: lane j carries rows j (unit A) and j+4 (unit B)
#pragma unroll
        for (int m = 0; m < 4; ++m) {
            p[m]     += (j == m) ? xg_cur[0] : 0.f;
            p[m + 4] += (j == m) ? xg_cur[1] : 0.f;
        }

        // quad butterfly: xor1 -> keep-by-bit0 -> xor2 -> keep-by-bit1;
        // lane j ends with full sums of rows {j, j+4}
        float u[8];
#pragma unroll
        for (int m = 0; m < 8; ++m) u[m] = p[m] + dpp_xor1(p[m]);
        const bool bit0 = (j & 1);
        float a0 = bit0 ? u[1] : u[0];    // row (j&1)
        float a1 = bit0 ? u[3] : u[2];    // row (j&1)+2
        float a2 = bit0 ? u[5] : u[4];    // row (j&1)+4
        float a3 = bit0 ? u[7] : u[6];    // row (j&1)+6
        float A0 = a0 + dpp_xor2(a0);
        float A1 = a1 + dpp_xor2(a1);
        float A2 = a2 + dpp_xor2(a2);
        float A3 = a3 + dpp_xor2(a3);
        const bool bit1 = (j & 2);
        float preA = bit1 ? A1 : A0;      // row j   = gate j of unit 2Q
        float preB = bit1 ? A3 : A2;      // row j+4 = gate j of unit 2Q+1

        // redistribute gates within quad (lane k holds gate k): 8 broadcasts
        float giA = dpp_bc0(preA), gfA = dpp_bc1(preA);
        float ggA = dpp_bc2(preA), goA = dpp_bc3(preA);
        float giB = dpp_bc0(preB), gfB = dpp_bc1(preB);
        float ggB = dpp_bc2(preB), goB = dpp_bc3(preB);

        // activations + cell update, both units (4-lane redundant: uniform)
        float siA = __builtin_amdgcn_rcpf(1.f + __expf(-giA));
        float sfA = __builtin_amdgcn_rcpf(1.f + __expf(-gfA));
        float soA = __builtin_amdgcn_rcpf(1.f + __expf(-goA));
        float egA = __expf(2.f * ggA);
        float tgA = 1.f - 2.f * __builtin_amdgcn_rcpf(egA + 1.f);
        cA = sfA * cA + siA * tgA;
        float ecA = __expf(2.f * cA);
        float tcA = 1.f - 2.f * __builtin_amdgcn_rcpf(ecA + 1.f);
        hA = soA * tcA;

        float siB = __builtin_amdgcn_rcpf(1.f + __expf(-giB));
        float sfB = __builtin_amdgcn_rcpf(1.f + __expf(-gfB));
        float soB = __builtin_amdgcn_rcpf(1.f + __expf(-goB));
        float egB = __expf(2.f * ggB);
        float tgB = 1.f - 2.f * __builtin_amdgcn_rcpf(egB + 1.f);
        cB = sfB * cB + siB * tgB;
        float ecB = __expf(2.f * cB);
        float tcB = 1.f - 2.f * __builtin_amdgcn_rcpf(ecB + 1.f);
        hB = soB * tcB;

        // pack both units' h, one writer per quad (16 consecutive banks/wave)
        const int nxt = (t + 1) & 1;
        if (j == 0)
            *(unsigned int*)((char*)hbf[nxt] + 4 * Q) = cvt_pk_bf16(hA, hB);
        __syncthreads();                               // single barrier/step

        xg_cur = xg_nxt;
        xg_nxt = xg_n2;
    }

    // head needs f32 h_T: park both units, then 2-thread dot
    if (j == 0) { hf[2 * Q] = hA; hf[2 * Q + 1] = hB; }
    __syncthreads();
    if (tid < 2) {
        const f32x4* wf = (const f32x4*)(Wfc + tid * HIDDEN);
        const f32x4* h4 = (const f32x4*)hf;
        f32x4 s = {0.f, 0.f, 0.f, 0.f};
#pragma unroll
        for (int k = 0; k < 32; ++k) s += wf[k] * h4[k];
        out[b * 2 + tid] = bfc[tid] + ((s[0] + s[1]) + (s[2] + s[3]));
    }
}

extern "C" void kernel_launch(void* const* d_in, const int* in_sizes, int n_in,
                              void* d_out, int out_size, void* d_ws, size_t ws_size,
                              hipStream_t stream) {
    (void)in_sizes; (void)n_in; (void)out_size; (void)ws_size;
    const int*   x   = (const int*)d_in[0];
    const float* emb = (const float*)d_in[1];
    const float* Wih = (const float*)d_in[2];
    const float* Whh = (const float*)d_in[3];
    const float* bih = (const float*)d_in[4];
    const float* bhh = (const float*)d_in[5];
    const float* Wfc = (const float*)d_in[6];
    const float* bfc = (const float*)d_in[7];
    float* out   = (float*)d_out;
    float* table = (float*)d_ws;    // 50257*512*4 B = 98.2 MB scratch

    const int mTiles = (VOCAB + K1_BM - 1) / K1_BM;   // 393
    const int nTiles = G4 / K1_BN;                    // 8
    table_gemm<<<dim3(mTiles * nTiles), 256, 0, stream>>>(emb, Wih, bih, bhh, table);
    lstm_seq<<<dim3(BATCH), 256, 0, stream>>>(x, table, Whh, Wfc, bfc, out);
}